// Round 6
// baseline (682.757 us; speedup 1.0000x reference)
//
#include <hip/hip_runtime.h>
#include <cmath>

#define BB 256
#define TT 512
#define NN 128
#define LN2F 0.6931471805599453f

__device__ __forceinline__ float wave_max64(float v) {
    #pragma unroll
    for (int off = 32; off; off >>= 1) v = fmaxf(v, __shfl_xor(v, off));
    return v;
}
__device__ __forceinline__ float wave_sum64(float v) {
    #pragma unroll
    for (int off = 32; off; off >>= 1) v += __shfl_xor(v, off);
    return v;
}
// argmax over 128 values (lane l holds indices 2l, 2l+1); first-index tie-break.
__device__ __forceinline__ int wave_argmax128(float v0, float v1, int l) {
    float m = fmaxf(v0, v1);
    float wm = wave_max64(m);
    unsigned long long ball = __ballot(m == wm);
    int lane = __ffsll(ball) - 1;
    int idx = (v0 == wm) ? (2 * l) : (2 * l + 1);
    return __shfl(idx, lane);
}

// Padded state layout: 32-float chunk c starts at word 36c (bank offset 4c).
__device__ __forceinline__ int padidx(int i) { return 36 * (i >> 5) + (i & 31); }

// Forward. grid = 2*BB, 512-thread blocks (8 waves).
//   Even blocks: Viterbi with u8 backpointers in LDS + parallel backtrace.
//   Odd blocks:  log-norm chain (linear domain, col-0 power-of-2 pivot).
// Independent barrier domains; 2 blocks/CU = 16 waves (LDS 2x71KB fits 160KB).
// Column j = (l&15)+16w, i-chunk q = l>>4 (32 i's); combine via shfl_xor(16/32).
__global__ __launch_bounds__(512, 2) void fwd_kernel(
        const float* __restrict__ em, const int* __restrict__ mask,
        const float* __restrict__ trans, float* __restrict__ outp,
        float* __restrict__ lognorm) {
    const int bi = blockIdx.x;
    const int b = bi >> 1;
    const bool isV = (bi & 1) == 0;
    const int tid = threadIdx.x;
    const int w = tid >> 6;
    const int l = tid & 63;
    const int j = (l & 15) + 16 * w;
    const int q = l >> 4;
    const int i0 = 32 * q;

    float C[32];  // V: trans[i0+r][j]; L: exp of it
    {
        const float* tc = trans + (size_t)i0 * NN + j;
        #pragma unroll
        for (int r = 0; r < 32; ++r) C[r] = tc[(size_t)r * NN];
        if (!isV) {
            #pragma unroll
            for (int r = 0; r < 32; ++r) C[r] = __expf(C[r]);
        }
    }

    __shared__ __align__(16) float stA[144], stB[144];  // ping-pong state
    __shared__ unsigned char bp_lds[TT * NN];           // 64 KB backpointers (V)
    __shared__ unsigned char tags_lds[TT];
    __shared__ unsigned char map_lds[8 * NN];           // chunk tag maps
    __shared__ int entry_sh[8];
    __shared__ int msk[TT];
    __shared__ float piv[2];
    __shared__ float sfin[NN];
    __shared__ int misc[2];                             // [0]=lastTag [1]=kacc

    msk[tid] = mask[b * TT + tid];

    const float* emb = em + (size_t)b * TT * NN;
    float st = 0.f;   // per-column state on writer lanes (V: alpha, L: s)
    int kacc = 0;
    {
        float a0 = emb[j];
        if (isV) {
            st = a0;
            if (l < 16) stA[padidx(j)] = a0;
        } else {
            st = __expf(a0);
            if (l < 16) stA[padidx(j)] = st;
            if (tid == 0) piv[0] = st;
        }
    }
    float e_next = emb[NN + j];
    __syncthreads();

    if (isV) {
        const float4* apA = (const float4*)(stA + 36 * q);
        const float4* apB = (const float4*)(stB + 36 * q);

        auto VSTEP = [&](int t, const float4* ap, float* dst) {
            const float e_cur = e_next;
            if (t + 1 < TT) e_next = emb[(size_t)(t + 1) * NN + j];
            const int m = msk[t];
            float m0 = -INFINITY, m1 = -INFINITY, m2 = -INFINITY, m3 = -INFINITY;
            int u0 = 0, u1 = 0, u2 = 0, u3 = 0;
            #pragma unroll
            for (int u = 0; u < 8; ++u) {
                float4 v = ap[u];
                float c0 = v.x + C[4*u+0]; u0 = (c0 > m0) ? u : u0; m0 = fmaxf(m0, c0);
                float c1 = v.y + C[4*u+1]; u1 = (c1 > m1) ? u : u1; m1 = fmaxf(m1, c1);
                float c2 = v.z + C[4*u+2]; u2 = (c2 > m2) ? u : u2; m2 = fmaxf(m2, c2);
                float c3 = v.w + C[4*u+3]; u3 = (c3 > m3) ? u : u3; m3 = fmaxf(m3, c3);
            }
            float bv = m0; int bx = i0 + 4 * u0;
            { int id = i0 + 4*u1 + 1; if (m1 > bv || (m1 == bv && id < bx)) { bv = m1; bx = id; } }
            { int id = i0 + 4*u2 + 2; if (m2 > bv || (m2 == bv && id < bx)) { bv = m2; bx = id; } }
            { int id = i0 + 4*u3 + 3; if (m3 > bv || (m3 == bv && id < bx)) { bv = m3; bx = id; } }
            #pragma unroll
            for (int off = 16; off <= 32; off <<= 1) {
                float ov = __shfl_xor(bv, off);
                int oi = __shfl_xor(bx, off);
                if (ov > bv || (ov == bv && oi < bx)) { bv = ov; bx = oi; }
            }
            if (l < 16) {
                float an; int bp;
                if (m) { an = bv + e_cur; bp = bx; }   // plain add = reference-exact
                else   { an = st;         bp = j;  }   // identity bp when masked
                st = an;
                dst[padidx(j)] = an;
                bp_lds[t * NN + j] = (unsigned char)bp;
            }
            __syncthreads();
        };

        for (int t = 1; t < TT - 1; t += 2) {
            VSTEP(t, apA, stB);
            VSTEP(t + 1, apB, stA);
        }
        VSTEP(TT - 1, apA, stB);   // final alpha in stB

        if (w == 0) {   // last-tag argmax (exact, first-index ties)
            float a0 = stB[padidx(2 * l)], a1 = stB[padidx(2 * l + 1)];
            int tg = wave_argmax128(a0, a1, l);
            if (l == 0) { misc[0] = tg; tags_lds[TT - 1] = (unsigned char)tg; }
        }
        // Phase 1: each wave speculatively maps all 128 entry tags through its
        // 64-step chunk (two interleaved independent chains per lane).
        const int lo = 64 * w + 1;
        const int hi = (w == 7) ? (TT - 1) : (64 * w + 64);
        {
            int tA = 2 * l, tB = 2 * l + 1;
            for (int t = hi; t >= lo; --t) {
                tA = bp_lds[t * NN + tA];
                tB = bp_lds[t * NN + tB];
            }
            map_lds[w * NN + 2 * l]     = (unsigned char)tA;
            map_lds[w * NN + 2 * l + 1] = (unsigned char)tB;
        }
        __syncthreads();
        // Phase 2: compose chunk maps to get true entry tag per chunk.
        if (tid == 0) {
            int e = misc[0];
            entry_sh[7] = e;
            for (int c = 7; c >= 1; --c) { e = map_lds[c * NN + e]; entry_sh[c - 1] = e; }
        }
        __syncthreads();
        // Phase 3: re-trace each chunk from its true entry, writing tags.
        if (l == 0) {
            int tg = entry_sh[w];
            for (int t = hi; t >= lo; --t) {
                tg = bp_lds[t * NN + tg];
                tags_lds[t - 1] = (unsigned char)tg;
            }
        }
        __syncthreads();
        outp[(size_t)b * TT + tid] = (float)tags_lds[tid];
    } else {
        const float4* spA = (const float4*)(stA + 36 * q);
        const float4* spB = (const float4*)(stB + 36 * q);

        auto LSTEP = [&](int t, const float4* sp, float* dst, int pp, int pq) {
            const float e_cur = e_next;
            if (t + 1 < TT) e_next = emb[(size_t)(t + 1) * NN + j];
            const int m = msk[t];
            const float pv = piv[pp];
            float d0 = 0, d1 = 0, d2 = 0, d3 = 0;
            #pragma unroll
            for (int u = 0; u < 8; ++u) {
                float4 v = sp[u];
                d0 = fmaf(v.x, C[4*u+0], d0);
                d1 = fmaf(v.y, C[4*u+1], d1);
                d2 = fmaf(v.z, C[4*u+2], d2);
                d3 = fmaf(v.w, C[4*u+3], d3);
            }
            float dot = (d0 + d1) + (d2 + d3);
            dot += __shfl_xor(dot, 16);
            dot += __shfl_xor(dot, 32);
            const int k = (int)(__float_as_uint(pv) >> 23) - 127;
            const float scale = __uint_as_float((unsigned)(127 - k) << 23);  // 2^-k
            float sn;
            if (m) { sn = dot * scale * __expf(e_cur); kacc += k; }
            else   { sn = st; }
            st = sn;
            if (l < 16) {
                dst[padidx(j)] = sn;
                if (tid == 0) piv[pq] = sn;   // column-0 pivot
            }
            __syncthreads();
        };

        for (int t = 1; t < TT - 1; t += 2) {
            LSTEP(t, spA, stB, 0, 1);
            LSTEP(t + 1, spB, stA, 1, 0);
        }
        LSTEP(TT - 1, spA, stB, 0, 1);

        if (l < 16) sfin[j] = st;
        if (tid == 0) misc[1] = kacc;
        __syncthreads();
        if (w == 0) {
            float v = sfin[2 * l] + sfin[2 * l + 1];
            v = wave_sum64(v);
            if (l == 0) lognorm[b] = __logf(v) + (float)misc[1] * LN2F;
        }
    }
}

// Gold-path score + final LL. One block (128 threads) per batch.
__global__ __launch_bounds__(128, 1) void score_kernel(
        const float* __restrict__ em, const int* __restrict__ tags,
        const int* __restrict__ mask, const float* __restrict__ trans,
        const float* __restrict__ lognorm, float* __restrict__ out_ll) {
    const int b = blockIdx.x;
    const int tid = threadIdx.x;
    float acc = 0.f;
    for (int t = tid; t < TT; t += 128) {
        int tg = tags[b * TT + t];
        float mf = (float)mask[b * TT + t];
        acc += em[((size_t)b * TT + t) * NN + tg] * mf;
        if (t >= 1) {
            int tp = tags[b * TT + t - 1];
            acc += trans[tp * NN + tg] * mf;
        }
    }
    acc = wave_sum64(acc);
    __shared__ float rs[2];
    if ((tid & 63) == 0) rs[tid >> 6] = acc;
    __syncthreads();
    if (tid == 0) out_ll[b] = (rs[0] + rs[1]) - lognorm[b];
}

__global__ void copy_trans_kernel(const float* __restrict__ trans,
                                  float* __restrict__ dst) {
    int i = blockIdx.x * 256 + threadIdx.x;
    if (i < NN * NN) dst[i] = trans[i];
}

extern "C" void kernel_launch(void* const* d_in, const int* in_sizes, int n_in,
                              void* d_out, int out_size, void* d_ws, size_t ws_size,
                              hipStream_t stream) {
    const float* em = (const float*)d_in[0];
    const int* tags = (const int*)d_in[1];
    const int* mask = (const int*)d_in[2];
    const float* trans = (const float*)d_in[3];

    float* out = (float*)d_out;
    float* out_ll = out;
    float* out_trans = out + BB;
    float* out_pred = out + BB + NN * NN;

    float* lognorm = (float*)d_ws;   // [256]

    hipLaunchKernelGGL(fwd_kernel, dim3(2 * BB), dim3(512), 0, stream,
                       em, mask, trans, out_pred, lognorm);
    hipLaunchKernelGGL(copy_trans_kernel, dim3(64), dim3(256), 0, stream,
                       trans, out_trans);
    hipLaunchKernelGGL(score_kernel, dim3(BB), dim3(128), 0, stream,
                       em, tags, mask, trans, lognorm, out_ll);
}

// Round 7
// 587.109 us; speedup vs baseline: 1.1629x; 1.1629x over previous
//
#include <hip/hip_runtime.h>
#include <cmath>

#define BB 256
#define TT 512
#define NN 128
#define LN2F 0.6931471805599453f

typedef __bf16 bf16x8 __attribute__((ext_vector_type(8)));
typedef float floatx4 __attribute__((ext_vector_type(4)));

__device__ __forceinline__ float wave_max64(float v) {
    #pragma unroll
    for (int off = 32; off; off >>= 1) v = fmaxf(v, __shfl_xor(v, off));
    return v;
}
__device__ __forceinline__ float wave_sum64(float v) {
    #pragma unroll
    for (int off = 32; off; off >>= 1) v += __shfl_xor(v, off);
    return v;
}
// argmax over 128 values (lane l holds indices 2l, 2l+1); first-index tie-break.
__device__ __forceinline__ int wave_argmax128(float v0, float v1, int l) {
    float m = fmaxf(v0, v1);
    float wm = wave_max64(m);
    unsigned long long ball = __ballot(m == wm);
    int lane = __ffsll(ball) - 1;
    int idx = (v0 == wm) ? (2 * l) : (2 * l + 1);
    return __shfl(idx, lane);
}

__device__ __forceinline__ __bf16 to_bf16(float f) {   // RNE
    unsigned u = __float_as_uint(f);
    unsigned r = (u + 0x7FFFu + ((u >> 16) & 1u)) >> 16;
    union { unsigned short s; __bf16 b; } cv;
    cv.s = (unsigned short)r;
    return cv.b;
}

// Padded state layout: 32-float chunk c starts at word 36c (bank offset 4c).
__device__ __forceinline__ int padidx(int i) { return 36 * (i >> 5) + (i & 31); }

// Forward: 1024 threads/batch, 16 waves, one barrier/step.
//   Waves 0-7 : Viterbi, col j=(l&15)+16w, i-chunk q=l>>4; exact fp32 + u8 bp.
//   Waves 8-15: log-norm via MFMA. Wave 8+g owns cols 16g..16g+15; E=exp(trans)
//               held as 4 bf16 B-fragments; s as bf16[128] in LDS (dbl-buffered).
//               All 16 A-rows identical -> every lane's D regs hold dot[col].
// Backtrace: 3-phase parallel (speculative chunk maps + compose + re-trace).
__global__ __launch_bounds__(1024, 4) void fwd_kernel(
        const float* __restrict__ em, const int* __restrict__ mask,
        const float* __restrict__ trans, float* __restrict__ outp,
        float* __restrict__ lognorm) {
    const int b = blockIdx.x;
    const int tid = threadIdx.x;
    const int w = tid >> 6;
    const int l = tid & 63;
    const bool isV = (w < 8);
    const int j = (l & 15) + 16 * (w & 7);   // column (V: unique; L: dup x4 quads)
    const int q = l >> 4;                    // V: i-chunk; L: quad
    const int i0 = 32 * q;

    __shared__ __align__(16) float apad[2][144];       // viterbi alpha ping-pong
    __shared__ __align__(16) __bf16 sbf[2][NN];        // log-norm s (bf16) dbl-buf
    __shared__ unsigned char bp_lds[TT * NN];          // 64 KB backpointers
    __shared__ unsigned char tags_lds[TT];
    __shared__ unsigned char map_lds[8 * NN];          // backtrace chunk maps
    __shared__ int entry_sh[8];
    __shared__ int msk[TT];
    __shared__ float piv[2];
    __shared__ float sfin[NN];
    __shared__ int misc[2];                            // [0]=lastTag [1]=kacc

    if (tid < TT) msk[tid] = mask[b * TT + tid];

    const float* emb = em + (size_t)b * TT * NN;

    // Per-role constant registers.
    float C[32];        // V only: trans[i0+r][j]
    bf16x8 Bf[4];       // L only: B-fragments of exp(trans) for 4 K-chunks
    if (isV) {
        const float* tc = trans + (size_t)i0 * NN + j;
        #pragma unroll
        for (int r = 0; r < 32; ++r) C[r] = tc[(size_t)r * NN];
    } else {
        #pragma unroll
        for (int kc = 0; kc < 4; ++kc) {
            #pragma unroll
            for (int jj = 0; jj < 8; ++jj) {
                int row = kc * 32 + q * 8 + jj;       // k index
                Bf[kc][jj] = to_bf16(__expf(trans[(size_t)row * NN + j]));
            }
        }
    }

    float st = 0.f;   // V: alpha (writer lanes l<16); L: fp32 s (lanes q==0)
    int kacc = 0;
    {
        float a0 = emb[j];
        if (isV) {
            st = a0;
            if (l < 16) apad[0][padidx(j)] = a0;
        } else {
            st = __expf(a0);
            if (l < 16) sbf[0][j] = to_bf16(st);
            if (w == 8 && l == 0) piv[0] = st;
        }
    }
    float e_next = emb[NN + j];
    __syncthreads();

    for (int t = 1; t < TT; ++t) {
        const float e_cur = e_next;
        if (t + 1 < TT) e_next = emb[(size_t)(t + 1) * NN + j];
        const int m = msk[t];
        const int p = (t - 1) & 1, qb = t & 1;

        if (isV) {
            const float4* ap = (const float4*)(apad[p] + 36 * q);
            float m0 = -INFINITY, m1 = -INFINITY, m2 = -INFINITY, m3 = -INFINITY;
            int u0 = 0, u1 = 0, u2 = 0, u3 = 0;
            #pragma unroll
            for (int u = 0; u < 8; ++u) {
                float4 v = ap[u];
                float c0 = v.x + C[4*u+0]; u0 = (c0 > m0) ? u : u0; m0 = fmaxf(m0, c0);
                float c1 = v.y + C[4*u+1]; u1 = (c1 > m1) ? u : u1; m1 = fmaxf(m1, c1);
                float c2 = v.z + C[4*u+2]; u2 = (c2 > m2) ? u : u2; m2 = fmaxf(m2, c2);
                float c3 = v.w + C[4*u+3]; u3 = (c3 > m3) ? u : u3; m3 = fmaxf(m3, c3);
            }
            float bv = m0; int bx = i0 + 4 * u0;
            { int id = i0 + 4*u1 + 1; if (m1 > bv || (m1 == bv && id < bx)) { bv = m1; bx = id; } }
            { int id = i0 + 4*u2 + 2; if (m2 > bv || (m2 == bv && id < bx)) { bv = m2; bx = id; } }
            { int id = i0 + 4*u3 + 3; if (m3 > bv || (m3 == bv && id < bx)) { bv = m3; bx = id; } }
            #pragma unroll
            for (int off = 16; off <= 32; off <<= 1) {
                float ov = __shfl_xor(bv, off);
                int oi = __shfl_xor(bx, off);
                if (ov > bv || (ov == bv && oi < bx)) { bv = ov; bx = oi; }
            }
            if (l < 16) {
                float an; int bp;
                if (m) { an = bv + e_cur; bp = bx; }   // plain add = reference-exact
                else   { an = st;         bp = j;  }   // identity bp when masked
                st = an;
                apad[qb][padidx(j)] = an;
                bp_lds[t * NN + j] = (unsigned char)bp;
            }
        } else {
            if (m) {
                // A-fragments: identical across rows -> broadcast LDS reads.
                const __bf16* sp = sbf[p];
                floatx4 acc = {0.f, 0.f, 0.f, 0.f};
                #pragma unroll
                for (int kc = 0; kc < 4; ++kc) {
                    bf16x8 a = *(const bf16x8*)(sp + kc * 32 + q * 8);
                    acc = __builtin_amdgcn_mfma_f32_16x16x32_bf16(a, Bf[kc], acc, 0, 0, 0);
                }
                float dot = acc[0];                    // all regs equal (rows identical)
                const float pv = piv[p];
                const int k = (int)(__float_as_uint(pv) >> 23) - 127;
                const float scale = __uint_as_float((unsigned)(127 - k) << 23);  // 2^-k
                st = dot * scale * __expf(e_cur);
                if (w == 8 && l == 0) kacc += k;
            }
            if (l < 16) sbf[qb][j] = to_bf16(st);
            if (w == 8 && l == 0) piv[qb] = st;
        }
        __syncthreads();
    }

    // ---- epilogue ----
    if (!isV && l < 16) sfin[j] = st;
    if (w == 8 && l == 0) misc[1] = kacc;
    if (w == 0) {   // last-tag argmax over final alpha (in apad[1], TT-1 odd)
        float a0 = apad[1][padidx(2 * l)], a1 = apad[1][padidx(2 * l + 1)];
        int tg = wave_argmax128(a0, a1, l);
        if (l == 0) { misc[0] = tg; tags_lds[TT - 1] = (unsigned char)tg; }
    }
    __syncthreads();

    // Phase 1 (V waves): speculative 64-step chunk maps for all 128 entry tags.
    const int lo = 64 * (w & 7) + 1;
    const int hi = ((w & 7) == 7) ? (TT - 1) : (64 * (w & 7) + 64);
    if (isV) {
        int tA = 2 * l, tB = 2 * l + 1;
        for (int t = hi; t >= lo; --t) {
            tA = bp_lds[t * NN + tA];
            tB = bp_lds[t * NN + tB];
        }
        map_lds[(w & 7) * NN + 2 * l]     = (unsigned char)tA;
        map_lds[(w & 7) * NN + 2 * l + 1] = (unsigned char)tB;
    } else if (w == 8) {   // log-norm final reduction (off critical path)
        float v = sfin[2 * l] + sfin[2 * l + 1];
        v = wave_sum64(v);
        if (l == 0) lognorm[b] = __logf(v) + (float)misc[1] * LN2F;
    }
    __syncthreads();
    // Phase 2: compose chunk maps -> true entry tag per chunk.
    if (tid == 0) {
        int e = misc[0];
        entry_sh[7] = e;
        for (int c = 7; c >= 1; --c) { e = map_lds[c * NN + e]; entry_sh[c - 1] = e; }
    }
    __syncthreads();
    // Phase 3: re-trace each chunk from its true entry.
    if (isV && l == 0) {
        int tg = entry_sh[w];
        for (int t = hi; t >= lo; --t) {
            tg = bp_lds[t * NN + tg];
            tags_lds[t - 1] = (unsigned char)tg;
        }
    }
    __syncthreads();
    if (tid < TT) outp[(size_t)b * TT + tid] = (float)tags_lds[tid];
}

// Gold-path score + final LL. One block (128 threads) per batch.
__global__ __launch_bounds__(128, 1) void score_kernel(
        const float* __restrict__ em, const int* __restrict__ tags,
        const int* __restrict__ mask, const float* __restrict__ trans,
        const float* __restrict__ lognorm, float* __restrict__ out_ll) {
    const int b = blockIdx.x;
    const int tid = threadIdx.x;
    float acc = 0.f;
    for (int t = tid; t < TT; t += 128) {
        int tg = tags[b * TT + t];
        float mf = (float)mask[b * TT + t];
        acc += em[((size_t)b * TT + t) * NN + tg] * mf;
        if (t >= 1) {
            int tp = tags[b * TT + t - 1];
            acc += trans[tp * NN + tg] * mf;
        }
    }
    acc = wave_sum64(acc);
    __shared__ float rs[2];
    if ((tid & 63) == 0) rs[tid >> 6] = acc;
    __syncthreads();
    if (tid == 0) out_ll[b] = (rs[0] + rs[1]) - lognorm[b];
}

__global__ void copy_trans_kernel(const float* __restrict__ trans,
                                  float* __restrict__ dst) {
    int i = blockIdx.x * 256 + threadIdx.x;
    if (i < NN * NN) dst[i] = trans[i];
}

extern "C" void kernel_launch(void* const* d_in, const int* in_sizes, int n_in,
                              void* d_out, int out_size, void* d_ws, size_t ws_size,
                              hipStream_t stream) {
    const float* em = (const float*)d_in[0];
    const int* tags = (const int*)d_in[1];
    const int* mask = (const int*)d_in[2];
    const float* trans = (const float*)d_in[3];

    float* out = (float*)d_out;
    float* out_ll = out;
    float* out_trans = out + BB;
    float* out_pred = out + BB + NN * NN;

    float* lognorm = (float*)d_ws;   // [256]

    hipLaunchKernelGGL(fwd_kernel, dim3(BB), dim3(1024), 0, stream,
                       em, mask, trans, out_pred, lognorm);
    hipLaunchKernelGGL(copy_trans_kernel, dim3(64), dim3(256), 0, stream,
                       trans, out_trans);
    hipLaunchKernelGGL(score_kernel, dim3(BB), dim3(128), 0, stream,
                       em, tags, mask, trans, lognorm, out_ll);
}